// Round 13
// baseline (1597.332 us; speedup 1.0000x reference)
//
#include <hip/hip_runtime.h>

#define SLOTS 7
#define BATCH 8192

typedef __attribute__((ext_vector_type(8))) __bf16 bf16x8;
typedef __attribute__((ext_vector_type(4))) float f32x4;

__device__ __forceinline__ void gl_lds16(const __bf16* g, __bf16* l) {
  __builtin_amdgcn_global_load_lds(
      (const __attribute__((address_space(1))) void*)g,
      (__attribute__((address_space(3))) void*)l, 16, 0, 0);
}

__device__ __forceinline__ float sigmoidf_(float x) {
  return 1.f / (1.f + __expf(-x));
}
__device__ __forceinline__ float tanhf_(float x) {
  float xc = fminf(fmaxf(x, -15.f), 15.f);
  float e = __expf(2.f * xc);
  return (e - 1.f) / (e + 1.f);
}

// bijective XCD swizzle (m157/m204): requires NB % 8 == 0 (all our grids).
__device__ __forceinline__ void xcd_remap(int& bx, int& by) {
  const int NBx = gridDim.x;
  const int NB = NBx * gridDim.y;
  int id = by * NBx + bx;
  id = (id & 7) * (NB >> 3) + (id >> 3);
  bx = id % NBx;
  by = id / NBx;
}

// ---------------------------------------------------------------------------
// gemm0_fused: 128x128 2-phase GEMM, grid (24,64). Blocks bx<16: LSTM path
// (B=WA, K=1792, gate-interleaved LSTM epilogue -> h0new,c0). Blocks bx>=16:
// aux path (B=WX, K=1280, bf16 store -> ghw). Held under the register cliff
// (r10/r11: 56 VGPR + 64 AGPR <= 128 -> 4 blk/CU). r7-verified 0-conflict
// chunk swizzle, both-sides (rule #21).
// ---------------------------------------------------------------------------
__global__ void __launch_bounds__(256, 4)
gemm0_fused(const __bf16* __restrict__ A, int lda,
            const __bf16* __restrict__ WA, const __bf16* __restrict__ WX,
            const float* __restrict__ b_ih, const float* __restrict__ b_hh,
            float* __restrict__ cst, __bf16* __restrict__ hout, int hld, int hoff,
            __bf16* __restrict__ ghw) {
  __shared__ __align__(16) __bf16 As[2][128 * 32];
  __shared__ __align__(16) __bf16 Bs[2][128 * 32];
  const int w = threadIdx.x >> 6;
  const int lane = threadIdx.x & 63;
  const int wr = w >> 1, wc = w & 1;
  int bx = blockIdx.x, by = blockIdx.y;
  xcd_remap(bx, by);
  const bool isAux = (bx >= 16);
  const int rowBase = by << 7;
  const int colBase = (isAux ? (bx - 16) : bx) << 7;
  const __bf16* Bw = isAux ? WX : WA;
  const int ldb = isAux ? 1280 : 1792;
  const int nsteps = (isAux ? 1280 : 1792) >> 5;
  const int sr = lane >> 2;
  const int scs = (((lane & 3) ^ ((sr >> 1) & 3)) << 3);  // swizzled src chunk

  f32x4 acc[4][4];
#pragma unroll
  for (int i = 0; i < 4; ++i)
#pragma unroll
    for (int j = 0; j < 4; ++j) acc[i][j] = (f32x4){0.f, 0.f, 0.f, 0.f};

#define STAGE(bi, k0)                                                            \
  {                                                                              \
    const __bf16* ga = A + (size_t)(rowBase + (w << 5) + sr) * lda + (k0) + scs; \
    gl_lds16(ga, &As[(bi)][(w << 5) * 32]);                                      \
    gl_lds16(ga + (size_t)16 * lda, &As[(bi)][((w << 5) + 16) * 32]);            \
    const __bf16* gb = Bw + (size_t)(colBase + (w << 5) + sr) * ldb + (k0) + scs;\
    gl_lds16(gb, &Bs[(bi)][(w << 5) * 32]);                                      \
    gl_lds16(gb + (size_t)16 * ldb, &Bs[(bi)][((w << 5) + 16) * 32]);            \
  }

  STAGE(0, 0);
  __syncthreads();
  int buf = 0;
  const int ln = lane & 15;
  const int lh = lane >> 4;
  const int swz = ((lh ^ ((ln >> 1) & 3)) << 3);  // swizzled read offset
  for (int t = 0; t < nsteps; ++t) {
    if (t + 1 < nsteps) STAGE(buf ^ 1, (t + 1) << 5);
    bf16x8 av[4], bv[4];
#pragma unroll
    for (int i = 0; i < 4; ++i)
      av[i] = *(const bf16x8*)&As[buf][((wr << 6) + (i << 4) + ln) * 32 + swz];
#pragma unroll
    for (int i = 0; i < 4; ++i)
      bv[i] = *(const bf16x8*)&Bs[buf][((wc << 6) + (i << 4) + ln) * 32 + swz];
#pragma unroll
    for (int mi = 0; mi < 4; ++mi)
#pragma unroll
      for (int ni = 0; ni < 4; ++ni)
        acc[mi][ni] = __builtin_amdgcn_mfma_f32_16x16x32_bf16(
            av[mi], bv[ni], acc[mi][ni], 0, 0, 0);
    __syncthreads();
    buf ^= 1;
  }
#undef STAGE

  const int row0 = rowBase + (wr << 6) + (lh << 2);
  if (!isAux) {  // fused gate-interleaved LSTM epilogue
    const int h = (((colBase >> 6) + wc) << 4) + ln;
    const float bs0 = b_ih[h] + b_hh[h];
    const float bs1 = b_ih[512 + h] + b_hh[512 + h];
    const float bs2 = b_ih[1024 + h] + b_hh[1024 + h];
    const float bs3 = b_ih[1536 + h] + b_hh[1536 + h];
#pragma unroll
    for (int mi = 0; mi < 4; ++mi)
#pragma unroll
      for (int r = 0; r < 4; ++r) {
        const int row = row0 + (mi << 4) + r;
        float gi = sigmoidf_(acc[mi][0][r] + bs0);
        float gf = sigmoidf_(acc[mi][1][r] + bs1);
        float gg = tanhf_(acc[mi][2][r] + bs2);
        float go = sigmoidf_(acc[mi][3][r] + bs3);
        const size_t ci = (size_t)row * 512 + h;
        float cn = gf * cst[ci] + gi * gg;
        cst[ci] = cn;
        hout[(size_t)row * hld + hoff + h] = (__bf16)(go * tanhf_(cn));
      }
  } else {  // aux: bf16 store to ghw (ld 1024)
    const int col0 = colBase + (wc << 6) + ln;
#pragma unroll
    for (int mi = 0; mi < 4; ++mi)
#pragma unroll
      for (int ni = 0; ni < 4; ++ni) {
        const int col = col0 + (ni << 4);
#pragma unroll
        for (int r = 0; r < 4; ++r)
          ghw[(size_t)(row0 + (mi << 4) + r) * 1024 + col] =
              (__bf16)acc[mi][ni][r];
      }
  }
}

// ---------------------------------------------------------------------------
// gemm_lstm: 128x128 2-phase GEMM + fused LSTM epilogue (GEMM1). Same core.
// ---------------------------------------------------------------------------
__global__ void __launch_bounds__(256, 4)
gemm_lstm(const __bf16* __restrict__ A, int lda,
          const __bf16* __restrict__ Bw, int ldb,
          const float* __restrict__ b_ih, const float* __restrict__ b_hh,
          float* __restrict__ cst, __bf16* __restrict__ hout, int hld, int hoff,
          int K) {
  __shared__ __align__(16) __bf16 As[2][128 * 32];
  __shared__ __align__(16) __bf16 Bs[2][128 * 32];
  const int w = threadIdx.x >> 6;
  const int lane = threadIdx.x & 63;
  const int wr = w >> 1, wc = w & 1;
  int bx = blockIdx.x, by = blockIdx.y;
  xcd_remap(bx, by);
  const int rowBase = by << 7;
  const int colBase = bx << 7;
  const int sr = lane >> 2;
  const int scs = (((lane & 3) ^ ((sr >> 1) & 3)) << 3);

  f32x4 acc[4][4];
#pragma unroll
  for (int i = 0; i < 4; ++i)
#pragma unroll
    for (int j = 0; j < 4; ++j) acc[i][j] = (f32x4){0.f, 0.f, 0.f, 0.f};

  const int nsteps = K >> 5;

#define STAGE(bi, k0)                                                            \
  {                                                                              \
    const __bf16* ga = A + (size_t)(rowBase + (w << 5) + sr) * lda + (k0) + scs; \
    gl_lds16(ga, &As[(bi)][(w << 5) * 32]);                                      \
    gl_lds16(ga + (size_t)16 * lda, &As[(bi)][((w << 5) + 16) * 32]);            \
    const __bf16* gb = Bw + (size_t)(colBase + (w << 5) + sr) * ldb + (k0) + scs;\
    gl_lds16(gb, &Bs[(bi)][(w << 5) * 32]);                                      \
    gl_lds16(gb + (size_t)16 * ldb, &Bs[(bi)][((w << 5) + 16) * 32]);            \
  }

  STAGE(0, 0);
  __syncthreads();
  int buf = 0;
  const int ln = lane & 15;
  const int lh = lane >> 4;
  const int swz = ((lh ^ ((ln >> 1) & 3)) << 3);
  for (int t = 0; t < nsteps; ++t) {
    if (t + 1 < nsteps) STAGE(buf ^ 1, (t + 1) << 5);
    bf16x8 av[4], bv[4];
#pragma unroll
    for (int i = 0; i < 4; ++i)
      av[i] = *(const bf16x8*)&As[buf][((wr << 6) + (i << 4) + ln) * 32 + swz];
#pragma unroll
    for (int i = 0; i < 4; ++i)
      bv[i] = *(const bf16x8*)&Bs[buf][((wc << 6) + (i << 4) + ln) * 32 + swz];
#pragma unroll
    for (int mi = 0; mi < 4; ++mi)
#pragma unroll
      for (int ni = 0; ni < 4; ++ni)
        acc[mi][ni] = __builtin_amdgcn_mfma_f32_16x16x32_bf16(
            av[mi], bv[ni], acc[mi][ni], 0, 0, 0);
    __syncthreads();
    buf ^= 1;
  }
#undef STAGE

  const int row0 = rowBase + (wr << 6) + (lh << 2);
  const int h = (((colBase >> 6) + wc) << 4) + ln;
  const float bs0 = b_ih[h] + b_hh[h];
  const float bs1 = b_ih[512 + h] + b_hh[512 + h];
  const float bs2 = b_ih[1024 + h] + b_hh[1024 + h];
  const float bs3 = b_ih[1536 + h] + b_hh[1536 + h];
#pragma unroll
  for (int mi = 0; mi < 4; ++mi)
#pragma unroll
    for (int r = 0; r < 4; ++r) {
      const int row = row0 + (mi << 4) + r;
      float gi = sigmoidf_(acc[mi][0][r] + bs0);
      float gf = sigmoidf_(acc[mi][1][r] + bs1);
      float gg = tanhf_(acc[mi][2][r] + bs2);
      float go = sigmoidf_(acc[mi][3][r] + bs3);
      const size_t ci = (size_t)row * 512 + h;
      float cn = gf * cst[ci] + gi * gg;
      cst[ci] = cn;
      hout[(size_t)row * hld + hoff + h] = (__bf16)(go * tanhf_(cn));
    }
}

// ---------------------------------------------------------------------------
// gemm_hwy: 2-phase 128x128 GEMM, highway epilogue + fused teacher-forced
// embedding write (r12-validated MODE 6).
// ---------------------------------------------------------------------------
__global__ void __launch_bounds__(256)
gemm_hwy(const __bf16* __restrict__ A, int lda,
         const __bf16* __restrict__ Bw, int ldb,
         __bf16* __restrict__ Cout, int ldc,
         const float* __restrict__ bias,
         const __bf16* __restrict__ auxr,
         __bf16* __restrict__ hout, int hld, int hoff,
         const __bf16* __restrict__ hsrc,
         const float* __restrict__ embp, const int* __restrict__ labels,
         int do_emb) {
  __shared__ __align__(16) __bf16 As[2][128 * 32];
  __shared__ __align__(16) __bf16 Bs[2][128 * 32];
  const int w = threadIdx.x >> 6;
  const int lane = threadIdx.x & 63;
  const int wr = w >> 1, wc = w & 1;
  int bx = blockIdx.x, by = blockIdx.y;
  xcd_remap(bx, by);
  const int rowBase = by << 7;
  const int colBase = bx << 7;
  const int sr = lane >> 2;
  const int sc = (lane & 3) << 3;

  f32x4 acc[4][4];
#pragma unroll
  for (int i = 0; i < 4; ++i)
#pragma unroll
    for (int j = 0; j < 4; ++j) acc[i][j] = (f32x4){0.f, 0.f, 0.f, 0.f};

  const int nsteps = 512 >> 5;

#define STAGE(bi, k0)                                                           \
  {                                                                             \
    const __bf16* ga = A + (size_t)(rowBase + (w << 5) + sr) * lda + (k0) + sc; \
    gl_lds16(ga, &As[(bi)][(w << 5) * 32]);                                     \
    gl_lds16(ga + (size_t)16 * lda, &As[(bi)][((w << 5) + 16) * 32]);           \
    const __bf16* gb = Bw + (size_t)(colBase + (w << 5) + sr) * ldb + (k0) + sc;\
    gl_lds16(gb, &Bs[(bi)][(w << 5) * 32]);                                     \
    gl_lds16(gb + (size_t)16 * ldb, &Bs[(bi)][((w << 5) + 16) * 32]);           \
  }

  STAGE(0, 0);
  __syncthreads();
  int buf = 0;
  const int ln = lane & 15;
  const int kg = (lane >> 4) << 3;
  for (int t = 0; t < nsteps; ++t) {
    if (t + 1 < nsteps) STAGE(buf ^ 1, (t + 1) << 5);
    bf16x8 av[4], bv[4];
#pragma unroll
    for (int i = 0; i < 4; ++i)
      av[i] = *(const bf16x8*)&As[buf][((wr << 6) + (i << 4) + ln) * 32 + kg];
#pragma unroll
    for (int i = 0; i < 4; ++i)
      bv[i] = *(const bf16x8*)&Bs[buf][((wc << 6) + (i << 4) + ln) * 32 + kg];
#pragma unroll
    for (int mi = 0; mi < 4; ++mi)
#pragma unroll
      for (int ni = 0; ni < 4; ++ni)
        acc[mi][ni] = __builtin_amdgcn_mfma_f32_16x16x32_bf16(
            av[mi], bv[ni], acc[mi][ni], 0, 0, 0);
    __syncthreads();
    buf ^= 1;
  }
#undef STAGE

  const int lh = lane >> 4;
  const int row0 = rowBase + (wr << 6) + (lh << 2);
  const int col0 = colBase + (wc << 6) + ln;
#pragma unroll
  for (int mi = 0; mi < 4; ++mi)
#pragma unroll
    for (int ni = 0; ni < 4; ++ni) {
      const int col = col0 + (ni << 4);
#pragma unroll
      for (int r = 0; r < 4; ++r) {
        const int row = row0 + (mi << 4) + r;
        float xp = (float)auxr[(size_t)row * 1024 + col];
        float hwl = (float)auxr[(size_t)row * 1024 + 512 + col];
        float gn = sigmoidf_(acc[mi][ni][r] + xp + bias[col]);
        float hn = (float)hsrc[(size_t)row * 512 + col];
        Cout[(size_t)row * ldc + col] = (__bf16)(gn * hn + (1.f - gn) * hwl);
        hout[(size_t)row * hld + hoff + col] = (__bf16)hn;  // h0 -> xh
      }
    }
  // teacher-forced embedding: cols 0..255 covered once by colBase<256 blocks
  if (do_emb && colBase < 256) {
#pragma unroll
    for (int mi = 0; mi < 4; ++mi)
#pragma unroll
      for (int r = 0; r < 4; ++r) {
        const int row = row0 + (mi << 4) + r;
        const int lab = labels[row];
#pragma unroll
        for (int ni = 0; ni < 4; ++ni) {
          const int col = col0 + (ni << 4);
          hout[(size_t)row * hld + 1024 + col] =
              (__bf16)embp[(size_t)lab * 256 + col];
        }
      }
  }
}

// ---------------------------------------------------------------------------
// head_fused: sh + pred in one kernel. Grid 64 blocks x 512 threads (8 waves).
// Phase A (8 waves, 2Mx4N of 64x64): hidden[128x256] = relu(h1@WS^T + sh_b)
//   -> LDS hid[128][264] (264: 16B-aligned rows, modest 8-way on reads).
// Phase B (4 waves, 2x2): out[128x100] = hidden @ WP^T + pred_b; WP read from
//   global (64 KB, L1/L2-resident). hidden never touches HBM.
// ---------------------------------------------------------------------------
__global__ void __launch_bounds__(512)
head_fused(const __bf16* __restrict__ h1, int lda,
           const __bf16* __restrict__ WS, const float* __restrict__ sh_b,
           const __bf16* __restrict__ WP, const float* __restrict__ pred_b,
           float* __restrict__ out) {
  extern __shared__ __bf16 dls[];
  __bf16* As = dls;                // 2 x 128x32 = 8192
  __bf16* Bs = dls + 8192;         // 2 x 256x32 = 16384
  __bf16* hid = dls + 24576;       // 128 x 264 = 33792
  const int w = threadIdx.x >> 6;
  const int lane = threadIdx.x & 63;
  const int wr = w >> 2, wc = w & 3;  // phase A: 2M x 4N waves
  const int rowBase = blockIdx.x << 7;
  const int sr = lane >> 2;
  const int sc = (lane & 3) << 3;
  const int ln = lane & 15;
  const int lh = lane >> 4;
  const int kg = lh << 3;

  f32x4 acc[4][4];
#pragma unroll
  for (int i = 0; i < 4; ++i)
#pragma unroll
    for (int j = 0; j < 4; ++j) acc[i][j] = (f32x4){0.f, 0.f, 0.f, 0.f};

  // phase A staging: A 128 rows (1 load/wave), B 256 rows (2 loads/wave)
#define STAGEH(bi, k0)                                                          \
  {                                                                             \
    const __bf16* ga = h1 + (size_t)(rowBase + (w << 4) + sr) * lda + (k0) + sc;\
    gl_lds16(ga, As + (bi)*4096 + (w << 4) * 32);                               \
    const __bf16* gb = WS + (size_t)((w << 5) + sr) * 512 + (k0) + sc;          \
    gl_lds16(gb, Bs + (bi)*8192 + (w << 5) * 32);                               \
    gl_lds16(gb + (size_t)16 * 512, Bs + (bi)*8192 + ((w << 5) + 16) * 32);     \
  }

  STAGEH(0, 0);
  __syncthreads();
  int buf = 0;
  for (int t = 0; t < 16; ++t) {  // K = 512
    if (t + 1 < 16) STAGEH(buf ^ 1, (t + 1) << 5);
    bf16x8 av[4], bv[4];
#pragma unroll
    for (int i = 0; i < 4; ++i)
      av[i] = *(const bf16x8*)&As[buf * 4096 + ((wr << 6) + (i << 4) + ln) * 32 + kg];
#pragma unroll
    for (int i = 0; i < 4; ++i)
      bv[i] = *(const bf16x8*)&Bs[buf * 8192 + ((wc << 6) + (i << 4) + ln) * 32 + kg];
#pragma unroll
    for (int mi = 0; mi < 4; ++mi)
#pragma unroll
      for (int ni = 0; ni < 4; ++ni)
        acc[mi][ni] = __builtin_amdgcn_mfma_f32_16x16x32_bf16(
            av[mi], bv[ni], acc[mi][ni], 0, 0, 0);
    __syncthreads();
    buf ^= 1;
  }
#undef STAGEH

  // epilogue A: relu + bias -> hid LDS
  {
    const int rl0 = (wr << 6) + (lh << 2);
    const int cl0 = (wc << 6) + ln;
#pragma unroll
    for (int mi = 0; mi < 4; ++mi)
#pragma unroll
      for (int ni = 0; ni < 4; ++ni) {
        const int col = cl0 + (ni << 4);
        const float b = sh_b[col];
#pragma unroll
        for (int r = 0; r < 4; ++r) {
          float v = fmaxf(acc[mi][ni][r] + b, 0.f);
          hid[(rl0 + (mi << 4) + r) * 264 + col] = (__bf16)v;
        }
      }
  }
  __syncthreads();

  // phase B: 4 waves compute out[128x128(100 real)] = hid @ WP^T + pred_b
  if (w < 4) {
    const int wr2 = w >> 1, wc2 = w & 1;
    f32x4 a2[4][4];
#pragma unroll
    for (int i = 0; i < 4; ++i)
#pragma unroll
      for (int j = 0; j < 4; ++j) a2[i][j] = (f32x4){0.f, 0.f, 0.f, 0.f};
    for (int t = 0; t < 8; ++t) {  // K = 256
      bf16x8 av[4], bv[4];
#pragma unroll
      for (int i = 0; i < 4; ++i)
        av[i] = *(const bf16x8*)&hid[((wr2 << 6) + (i << 4) + ln) * 264 + (t << 5) + kg];
#pragma unroll
      for (int i = 0; i < 4; ++i)
        bv[i] = *(const bf16x8*)&WP[(size_t)((wc2 << 6) + (i << 4) + ln) * 256 + (t << 5) + kg];
#pragma unroll
      for (int mi = 0; mi < 4; ++mi)
#pragma unroll
        for (int ni = 0; ni < 4; ++ni)
          a2[mi][ni] = __builtin_amdgcn_mfma_f32_16x16x32_bf16(
              av[mi], bv[ni], a2[mi][ni], 0, 0, 0);
    }
    const int row0 = rowBase + (wr2 << 6) + (lh << 2);
    const int col0 = (wc2 << 6) + ln;
#pragma unroll
    for (int mi = 0; mi < 4; ++mi)
#pragma unroll
      for (int ni = 0; ni < 4; ++ni) {
        const int col = col0 + (ni << 4);
        if (col < 100) {
          const float b = pred_b[col];
#pragma unroll
          for (int r = 0; r < 4; ++r)
            out[(size_t)(row0 + (mi << 4) + r) * 100 + col] =
                a2[mi][ni][r] + b;
        }
      }
  }
}

// ---------------------------------------------------------------------------
// pack_all: all 9 per-slot weight-pack regions in ONE launch (r10).
// ---------------------------------------------------------------------------
#define PR0 2621440
#define PR1 3670016
#define PR2 4325376
#define PR3 4980736
#define PR4 5242880
#define PR5 6291456
#define PR6 7340032
#define PR7 7471104
#define PR8 7503872
__global__ void pack_all(const float* __restrict__ W_ih0, const float* __restrict__ W_hh0,
                         const float* __restrict__ hwN_W0, const float* __restrict__ hwL_W0,
                         const float* __restrict__ W_ih1, const float* __restrict__ W_hh1,
                         const float* __restrict__ sh_W, const float* __restrict__ pred_W,
                         __bf16* __restrict__ WA, __bf16* __restrict__ WX,
                         __bf16* __restrict__ WH, __bf16* __restrict__ WB,
                         __bf16* __restrict__ WS, __bf16* __restrict__ WP, int s) {
  const int idx = blockIdx.x * 256 + threadIdx.x;
  if (idx >= PR8) return;
  if (idx < PR0) {
    int i = idx, r = i / 1280, c = i - r * 1280;
    int sr = (((r >> 4) & 3) << 9) + ((r >> 6) << 4) + (r & 15);
    WA[(long)r * 1792 + c] = (__bf16)W_ih0[(size_t)s * 2048 * 1280 + (long)sr * 1280 + c];
  } else if (idx < PR1) {
    int i = idx - PR0, r = i >> 9, c = i & 511;
    int sr = (((r >> 4) & 3) << 9) + ((r >> 6) << 4) + (r & 15);
    WA[(long)r * 1792 + 1280 + c] = (__bf16)W_hh0[(size_t)s * 2048 * 512 + (long)sr * 512 + c];
  } else if (idx < PR2) {
    int i = idx - PR1, r = i / 1280, c = i - r * 1280;
    WX[(long)r * 1280 + c] = (__bf16)hwN_W0[(size_t)s * 512 * 1792 + (long)r * 1792 + c];
  } else if (idx < PR3) {
    int i = idx - PR2, r = i / 1280, c = i - r * 1280;
    WX[(long)(512 + r) * 1280 + c] = (__bf16)hwL_W0[(size_t)s * 512 * 1280 + (long)r * 1280 + c];
  } else if (idx < PR4) {
    int i = idx - PR3, r = i >> 9, c = i & 511;
    WH[(long)r * 512 + c] = (__bf16)hwN_W0[(size_t)s * 512 * 1792 + (long)r * 1792 + 1280 + c];
  } else if (idx < PR5) {
    int i = idx - PR4, r = i >> 9, c = i & 511;
    int sr = (((r >> 4) & 3) << 9) + ((r >> 6) << 4) + (r & 15);
    WB[(long)r * 1024 + c] = (__bf16)W_ih1[(size_t)s * 2048 * 512 + (long)sr * 512 + c];
  } else if (idx < PR6) {
    int i = idx - PR5, r = i >> 9, c = i & 511;
    int sr = (((r >> 4) & 3) << 9) + ((r >> 6) << 4) + (r & 15);
    WB[(long)r * 1024 + 512 + c] = (__bf16)W_hh1[(size_t)s * 2048 * 512 + (long)sr * 512 + c];
  } else if (idx < PR7) {
    int i = idx - PR6, r = i >> 9, c = i & 511;
    WS[(long)r * 512 + c] = (__bf16)sh_W[(size_t)s * 256 * 512 + (long)r * 512 + c];
  } else {
    int i = idx - PR7, r = i >> 8, c = i & 255;
    float v = (r < 100) ? pred_W[(size_t)s * 100 * 256 + (long)r * 256 + c] : 0.f;
    WP[(long)r * 256 + c] = (__bf16)v;
  }
}

__global__ void conv_inputs(const float* __restrict__ in, __bf16* __restrict__ xh) {
  int idx = blockIdx.x * 256 + threadIdx.x;  // B*1024
  int b = idx >> 10, c = idx & 1023;
  xh[(size_t)b * 1792 + c] = (__bf16)in[idx];
}

__global__ void set_start(const float* __restrict__ start, __bf16* __restrict__ xh) {
  int idx = blockIdx.x * 256 + threadIdx.x;  // B*256
  int b = idx >> 8, e = idx & 255;
  xh[(size_t)b * 1792 + 1024 + e] = (__bf16)start[e];
}

__global__ void zero_states(__bf16* __restrict__ xh, __bf16* __restrict__ xh1A) {
  int idx = blockIdx.x * 256 + threadIdx.x;  // B*512
  int b = idx >> 9, h = idx & 511;
  xh[(size_t)b * 1792 + 1280 + h] = (__bf16)0.f;   // h0 = 0
  xh1A[(size_t)b * 1024 + 512 + h] = (__bf16)0.f;  // h1 = 0 (buffer 0)
}

extern "C" void kernel_launch(void* const* d_in, const int* in_sizes, int n_in,
                              void* d_out, int out_size, void* d_ws, size_t ws_size,
                              hipStream_t stream) {
  const float* inputs = (const float*)d_in[0];
  const int* labels = (const int*)d_in[1];
  const float* start = (const float*)d_in[2];
  const float* emb = (const float*)d_in[3];
  const float* W_ih0 = (const float*)d_in[4];
  const float* W_hh0 = (const float*)d_in[5];
  const float* b_ih0 = (const float*)d_in[6];
  const float* b_hh0 = (const float*)d_in[7];
  const float* hwN_W0 = (const float*)d_in[8];
  const float* hwN_b0 = (const float*)d_in[9];
  const float* hwL_W0 = (const float*)d_in[10];
  const float* W_ih1 = (const float*)d_in[11];
  const float* W_hh1 = (const float*)d_in[12];
  const float* b_ih1 = (const float*)d_in[13];
  const float* b_hh1 = (const float*)d_in[14];
  // d_in[15..17]: hwN_W1 / hwN_b1 / hwL_W1 — dead in reference, skipped
  const float* sh_W = (const float*)d_in[18];
  const float* sh_b = (const float*)d_in[19];
  const float* pred_W = (const float*)d_in[20];
  const float* pred_b = (const float*)d_in[21];
  float* out = (float*)d_out;

  char* p = (char*)d_ws;
  size_t off = 0;
  auto alloc = [&](size_t bytes) {
    void* r = p + off;
    off += (bytes + 255) & ~(size_t)255;
    return r;
  };
  __bf16* WA = (__bf16*)alloc((size_t)2048 * 1792 * 2);
  __bf16* WX = (__bf16*)alloc((size_t)1024 * 1280 * 2);
  __bf16* WH = (__bf16*)alloc((size_t)512 * 512 * 2);
  __bf16* WB = (__bf16*)alloc((size_t)2048 * 1024 * 2);
  __bf16* WS = (__bf16*)alloc((size_t)256 * 512 * 2);
  __bf16* WP = (__bf16*)alloc((size_t)128 * 256 * 2);
  __bf16* xh = (__bf16*)alloc((size_t)BATCH * 1792 * 2);
  __bf16* xh1A = (__bf16*)alloc((size_t)BATCH * 1024 * 2);
  __bf16* xh1B = (__bf16*)alloc((size_t)BATCH * 1024 * 2);
  __bf16* h0new = (__bf16*)alloc((size_t)BATCH * 512 * 2);
  __bf16* ghw = (__bf16*)alloc((size_t)BATCH * 1024 * 2);
  float* c0 = (float*)alloc((size_t)BATCH * 512 * 4);
  float* c1 = (float*)alloc((size_t)BATCH * 512 * 4);
  (void)ws_size; (void)in_sizes; (void)n_in; (void)out_size;

  hipMemsetAsync(c0, 0, (size_t)BATCH * 512 * 4, stream);
  hipMemsetAsync(c1, 0, (size_t)BATCH * 512 * 4, stream);
  zero_states<<<BATCH * 512 / 256, 256, 0, stream>>>(xh, xh1A);
  conv_inputs<<<BATCH * 1024 / 256, 256, 0, stream>>>(inputs, xh);
  set_start<<<BATCH * 256 / 256, 256, 0, stream>>>(start, xh);

  const dim3 blk(256);
  for (int s = 0; s < SLOTS; ++s) {
    __bf16* xcur = (s & 1) ? xh1B : xh1A;
    __bf16* xnext = (s & 1) ? xh1A : xh1B;
    // pack this slot's weights: single launch, 9 regions
    pack_all<<<(PR8 + 255) / 256, blk, 0, stream>>>(
        W_ih0, W_hh0, hwN_W0, hwL_W0, W_ih1, W_hh1, sh_W, pred_W,
        WA, WX, WH, WB, WS, WP, s);

    // GEMM0+aux fused: bx<16 -> LSTM-0 (h0new,c0); bx>=16 -> ghw (bf16)
    gemm0_fused<<<dim3(24, 64), blk, 0, stream>>>(
        xh, 1792, WA, WX, b_ih0 + s * 2048, b_hh0 + s * 2048,
        c0, h0new, 512, 0, ghw);
    // hwy: acc = h0new @ WH^T; highway -> cur; h0new -> xh; fused emb write
    gemm_hwy<<<dim3(4, 64), blk, 0, stream>>>(
        h0new, 512, WH, 512, xcur, 1024, hwN_b0 + s * 512,
        ghw, xh, 1792, 1280, h0new,
        emb + (size_t)s * 100 * 256, labels + (size_t)s * BATCH,
        (s < SLOTS - 1) ? 1 : 0);
    // GEMM1: [cur|h1] @ WB^T -> fused LSTM-1 (h -> xnext[:,512:1024], c1)
    gemm_lstm<<<dim3(16, 64), blk, 0, stream>>>(
        xcur, 1024, WB, 1024, b_ih1 + s * 2048, b_hh1 + s * 2048,
        c1, xnext, 1024, 512, 1024);
    // head: hidden = relu(h1@WS^T+b) in LDS; logits = hidden@WP^T+b -> out[s]
    head_fused<<<64, 512, 116736, stream>>>(
        xnext + 512, 1024, WS, sh_b + s * 256, WP, pred_b + s * 100,
        out + (size_t)s * BATCH * 100);
  }
}

// Round 14
// 1548.927 us; speedup vs baseline: 1.0313x; 1.0313x over previous
//
#include <hip/hip_runtime.h>

#define SLOTS 7
#define BATCH 8192

typedef __attribute__((ext_vector_type(8))) __bf16 bf16x8;
typedef __attribute__((ext_vector_type(4))) float f32x4;

__device__ __forceinline__ void gl_lds16(const __bf16* g, __bf16* l) {
  __builtin_amdgcn_global_load_lds(
      (const __attribute__((address_space(1))) void*)g,
      (__attribute__((address_space(3))) void*)l, 16, 0, 0);
}

__device__ __forceinline__ float sigmoidf_(float x) {
  return 1.f / (1.f + __expf(-x));
}
__device__ __forceinline__ float tanhf_(float x) {
  float xc = fminf(fmaxf(x, -15.f), 15.f);
  float e = __expf(2.f * xc);
  return (e - 1.f) / (e + 1.f);
}

// bijective XCD swizzle (m157/m204): requires NB % 8 == 0 (all our grids).
__device__ __forceinline__ void xcd_remap(int& bx, int& by) {
  const int NBx = gridDim.x;
  const int NB = NBx * gridDim.y;
  int id = by * NBx + bx;
  id = (id & 7) * (NB >> 3) + (id >> 3);
  bx = id % NBx;
  by = id / NBx;
}

// ---------------------------------------------------------------------------
// gemm_lstm: 128x128 2-phase GEMM + fused gate-interleaved LSTM epilogue,
// held under the register cliff (r10/r11): 56 VGPR + 64 AGPR <= 128 -> 4
// blk/CU via __launch_bounds__(256,4); bias loads AFTER the K-loop.
// r7-verified 0-conflict chunk swizzle (both-sides, rule #21).
// r13 lesson: do NOT fuse extra column panels into this dispatch — per-XCD
// working set must stay ~WA+xh (<= L2-ish); mixing WX in exploded FETCH
// 51->171 MB and cost +20%.
// Epilogue: col c -> gate (c>>4)&3 of unit h=(c>>6)*16+(c&15).
// ---------------------------------------------------------------------------
__global__ void __launch_bounds__(256, 4)
gemm_lstm(const __bf16* __restrict__ A, int lda,
          const __bf16* __restrict__ Bw, int ldb,
          const float* __restrict__ b_ih, const float* __restrict__ b_hh,
          float* __restrict__ cst, __bf16* __restrict__ hout, int hld, int hoff,
          int K) {
  __shared__ __align__(16) __bf16 As[2][128 * 32];
  __shared__ __align__(16) __bf16 Bs[2][128 * 32];
  const int w = threadIdx.x >> 6;
  const int lane = threadIdx.x & 63;
  const int wr = w >> 1, wc = w & 1;
  int bx = blockIdx.x, by = blockIdx.y;
  xcd_remap(bx, by);
  const int rowBase = by << 7;
  const int colBase = bx << 7;
  const int sr = lane >> 2;
  const int scs = (((lane & 3) ^ ((sr >> 1) & 3)) << 3);  // swizzled src chunk

  f32x4 acc[4][4];
#pragma unroll
  for (int i = 0; i < 4; ++i)
#pragma unroll
    for (int j = 0; j < 4; ++j) acc[i][j] = (f32x4){0.f, 0.f, 0.f, 0.f};

  const int nsteps = K >> 5;

#define STAGE(bi, k0)                                                            \
  {                                                                              \
    const __bf16* ga = A + (size_t)(rowBase + (w << 5) + sr) * lda + (k0) + scs; \
    gl_lds16(ga, &As[(bi)][(w << 5) * 32]);                                      \
    gl_lds16(ga + (size_t)16 * lda, &As[(bi)][((w << 5) + 16) * 32]);            \
    const __bf16* gb = Bw + (size_t)(colBase + (w << 5) + sr) * ldb + (k0) + scs;\
    gl_lds16(gb, &Bs[(bi)][(w << 5) * 32]);                                      \
    gl_lds16(gb + (size_t)16 * ldb, &Bs[(bi)][((w << 5) + 16) * 32]);            \
  }

  STAGE(0, 0);
  __syncthreads();
  int buf = 0;
  const int ln = lane & 15;
  const int lh = lane >> 4;
  const int swz = ((lh ^ ((ln >> 1) & 3)) << 3);  // swizzled read offset
  for (int t = 0; t < nsteps; ++t) {
    if (t + 1 < nsteps) STAGE(buf ^ 1, (t + 1) << 5);
    bf16x8 av[4], bv[4];
#pragma unroll
    for (int i = 0; i < 4; ++i)
      av[i] = *(const bf16x8*)&As[buf][((wr << 6) + (i << 4) + ln) * 32 + swz];
#pragma unroll
    for (int i = 0; i < 4; ++i)
      bv[i] = *(const bf16x8*)&Bs[buf][((wc << 6) + (i << 4) + ln) * 32 + swz];
#pragma unroll
    for (int mi = 0; mi < 4; ++mi)
#pragma unroll
      for (int ni = 0; ni < 4; ++ni)
        acc[mi][ni] = __builtin_amdgcn_mfma_f32_16x16x32_bf16(
            av[mi], bv[ni], acc[mi][ni], 0, 0, 0);
    __syncthreads();
    buf ^= 1;
  }
#undef STAGE

  const int row0 = rowBase + (wr << 6) + (lh << 2);
  const int h = (((colBase >> 6) + wc) << 4) + ln;
  const float bs0 = b_ih[h] + b_hh[h];
  const float bs1 = b_ih[512 + h] + b_hh[512 + h];
  const float bs2 = b_ih[1024 + h] + b_hh[1024 + h];
  const float bs3 = b_ih[1536 + h] + b_hh[1536 + h];
#pragma unroll
  for (int mi = 0; mi < 4; ++mi)
#pragma unroll
    for (int r = 0; r < 4; ++r) {
      const int row = row0 + (mi << 4) + r;
      float gi = sigmoidf_(acc[mi][0][r] + bs0);
      float gf = sigmoidf_(acc[mi][1][r] + bs1);
      float gg = tanhf_(acc[mi][2][r] + bs2);
      float go = sigmoidf_(acc[mi][3][r] + bs3);
      const size_t ci = (size_t)row * 512 + h;
      float cn = gf * cst[ci] + gi * gg;
      cst[ci] = cn;
      hout[(size_t)row * hld + hoff + h] = (__bf16)(go * tanhf_(cn));
    }
}

// ---------------------------------------------------------------------------
// gemm_aux: 2-phase 128x128 GEMM, bf16 plain store (ghw = x[:,0:1280]@WX^T).
// ---------------------------------------------------------------------------
__global__ void __launch_bounds__(256)
gemm_aux(const __bf16* __restrict__ A, int lda,
         const __bf16* __restrict__ Bw, int ldb,
         __bf16* __restrict__ Cout, int ldc, int K) {
  __shared__ __align__(16) __bf16 As[2][128 * 32];
  __shared__ __align__(16) __bf16 Bs[2][128 * 32];
  const int w = threadIdx.x >> 6;
  const int lane = threadIdx.x & 63;
  const int wr = w >> 1, wc = w & 1;
  int bx = blockIdx.x, by = blockIdx.y;
  xcd_remap(bx, by);
  const int rowBase = by << 7;
  const int colBase = bx << 7;
  const int sr = lane >> 2;
  const int sc = (lane & 3) << 3;

  f32x4 acc[4][4];
#pragma unroll
  for (int i = 0; i < 4; ++i)
#pragma unroll
    for (int j = 0; j < 4; ++j) acc[i][j] = (f32x4){0.f, 0.f, 0.f, 0.f};

  const int nsteps = K >> 5;

#define STAGE(bi, k0)                                                           \
  {                                                                             \
    const __bf16* ga = A + (size_t)(rowBase + (w << 5) + sr) * lda + (k0) + sc; \
    gl_lds16(ga, &As[(bi)][(w << 5) * 32]);                                     \
    gl_lds16(ga + (size_t)16 * lda, &As[(bi)][((w << 5) + 16) * 32]);           \
    const __bf16* gb = Bw + (size_t)(colBase + (w << 5) + sr) * ldb + (k0) + sc;\
    gl_lds16(gb, &Bs[(bi)][(w << 5) * 32]);                                     \
    gl_lds16(gb + (size_t)16 * ldb, &Bs[(bi)][((w << 5) + 16) * 32]);           \
  }

  STAGE(0, 0);
  __syncthreads();
  int buf = 0;
  const int ln = lane & 15;
  const int kg = (lane >> 4) << 3;
  for (int t = 0; t < nsteps; ++t) {
    if (t + 1 < nsteps) STAGE(buf ^ 1, (t + 1) << 5);
    bf16x8 av[4], bv[4];
#pragma unroll
    for (int i = 0; i < 4; ++i)
      av[i] = *(const bf16x8*)&As[buf][((wr << 6) + (i << 4) + ln) * 32 + kg];
#pragma unroll
    for (int i = 0; i < 4; ++i)
      bv[i] = *(const bf16x8*)&Bs[buf][((wc << 6) + (i << 4) + ln) * 32 + kg];
#pragma unroll
    for (int mi = 0; mi < 4; ++mi)
#pragma unroll
      for (int ni = 0; ni < 4; ++ni)
        acc[mi][ni] = __builtin_amdgcn_mfma_f32_16x16x32_bf16(
            av[mi], bv[ni], acc[mi][ni], 0, 0, 0);
    __syncthreads();
    buf ^= 1;
  }
#undef STAGE

  const int lh = lane >> 4;
  const int row0 = rowBase + (wr << 6) + (lh << 2);
  const int col0 = colBase + (wc << 6) + ln;
#pragma unroll
  for (int mi = 0; mi < 4; ++mi)
#pragma unroll
    for (int ni = 0; ni < 4; ++ni) {
      const int col = col0 + (ni << 4);
#pragma unroll
      for (int r = 0; r < 4; ++r)
        Cout[(size_t)(row0 + (mi << 4) + r) * ldc + col] = (__bf16)acc[mi][ni][r];
    }
}

// ---------------------------------------------------------------------------
// gemm_hwy: 2-phase 128x128 GEMM (K=512), highway epilogue + fused
// teacher-forced embedding write (r12-validated).
// ---------------------------------------------------------------------------
__global__ void __launch_bounds__(256)
gemm_hwy(const __bf16* __restrict__ A, int lda,
         const __bf16* __restrict__ Bw, int ldb,
         __bf16* __restrict__ Cout, int ldc,
         const float* __restrict__ bias,
         const __bf16* __restrict__ auxr,
         __bf16* __restrict__ hout, int hld, int hoff,
         const __bf16* __restrict__ hsrc,
         const float* __restrict__ embp, const int* __restrict__ labels,
         int do_emb) {
  __shared__ __align__(16) __bf16 As[2][128 * 32];
  __shared__ __align__(16) __bf16 Bs[2][128 * 32];
  const int w = threadIdx.x >> 6;
  const int lane = threadIdx.x & 63;
  const int wr = w >> 1, wc = w & 1;
  int bx = blockIdx.x, by = blockIdx.y;
  xcd_remap(bx, by);
  const int rowBase = by << 7;
  const int colBase = bx << 7;
  const int sr = lane >> 2;
  const int sc = (lane & 3) << 3;

  f32x4 acc[4][4];
#pragma unroll
  for (int i = 0; i < 4; ++i)
#pragma unroll
    for (int j = 0; j < 4; ++j) acc[i][j] = (f32x4){0.f, 0.f, 0.f, 0.f};

#define STAGE(bi, k0)                                                           \
  {                                                                             \
    const __bf16* ga = A + (size_t)(rowBase + (w << 5) + sr) * lda + (k0) + sc; \
    gl_lds16(ga, &As[(bi)][(w << 5) * 32]);                                     \
    gl_lds16(ga + (size_t)16 * lda, &As[(bi)][((w << 5) + 16) * 32]);           \
    const __bf16* gb = Bw + (size_t)(colBase + (w << 5) + sr) * ldb + (k0) + sc;\
    gl_lds16(gb, &Bs[(bi)][(w << 5) * 32]);                                     \
    gl_lds16(gb + (size_t)16 * ldb, &Bs[(bi)][((w << 5) + 16) * 32]);           \
  }

  STAGE(0, 0);
  __syncthreads();
  int buf = 0;
  const int ln = lane & 15;
  const int kg = (lane >> 4) << 3;
  for (int t = 0; t < 16; ++t) {  // K = 512
    if (t + 1 < 16) STAGE(buf ^ 1, (t + 1) << 5);
    bf16x8 av[4], bv[4];
#pragma unroll
    for (int i = 0; i < 4; ++i)
      av[i] = *(const bf16x8*)&As[buf][((wr << 6) + (i << 4) + ln) * 32 + kg];
#pragma unroll
    for (int i = 0; i < 4; ++i)
      bv[i] = *(const bf16x8*)&Bs[buf][((wc << 6) + (i << 4) + ln) * 32 + kg];
#pragma unroll
    for (int mi = 0; mi < 4; ++mi)
#pragma unroll
      for (int ni = 0; ni < 4; ++ni)
        acc[mi][ni] = __builtin_amdgcn_mfma_f32_16x16x32_bf16(
            av[mi], bv[ni], acc[mi][ni], 0, 0, 0);
    __syncthreads();
    buf ^= 1;
  }
#undef STAGE

  const int lh = lane >> 4;
  const int row0 = rowBase + (wr << 6) + (lh << 2);
  const int col0 = colBase + (wc << 6) + ln;
#pragma unroll
  for (int mi = 0; mi < 4; ++mi)
#pragma unroll
    for (int ni = 0; ni < 4; ++ni) {
      const int col = col0 + (ni << 4);
#pragma unroll
      for (int r = 0; r < 4; ++r) {
        const int row = row0 + (mi << 4) + r;
        float xp = (float)auxr[(size_t)row * 1024 + col];
        float hwl = (float)auxr[(size_t)row * 1024 + 512 + col];
        float gn = sigmoidf_(acc[mi][ni][r] + xp + bias[col]);
        float hn = (float)hsrc[(size_t)row * 512 + col];
        Cout[(size_t)row * ldc + col] = (__bf16)(gn * hn + (1.f - gn) * hwl);
        hout[(size_t)row * hld + hoff + col] = (__bf16)hn;  // h0 -> xh
      }
    }
  // teacher-forced embedding: cols 0..255 covered once by colBase<256 blocks
  if (do_emb && colBase < 256) {
#pragma unroll
    for (int mi = 0; mi < 4; ++mi)
#pragma unroll
      for (int r = 0; r < 4; ++r) {
        const int row = row0 + (mi << 4) + r;
        const int lab = labels[row];
#pragma unroll
        for (int ni = 0; ni < 4; ++ni) {
          const int col = col0 + (ni << 4);
          hout[(size_t)row * hld + 1024 + col] =
              (__bf16)embp[(size_t)lab * 256 + col];
        }
      }
  }
}

// ---------------------------------------------------------------------------
// head_fused (r13-validated win): sh + pred in one kernel. 64 blocks x 512.
// Phase A (8 waves): hidden[128x256] = relu(h1@WS^T + sh_b) -> LDS [128][264].
// Phase B (4 waves): out[128x100] = hidden @ WP^T + pred_b; WP from global.
// ---------------------------------------------------------------------------
__global__ void __launch_bounds__(512)
head_fused(const __bf16* __restrict__ h1, int lda,
           const __bf16* __restrict__ WS, const float* __restrict__ sh_b,
           const __bf16* __restrict__ WP, const float* __restrict__ pred_b,
           float* __restrict__ out) {
  extern __shared__ __bf16 dls[];
  __bf16* As = dls;           // 2 x 128x32 = 8192
  __bf16* Bs = dls + 8192;    // 2 x 256x32 = 16384
  __bf16* hid = dls + 24576;  // 128 x 264 = 33792
  const int w = threadIdx.x >> 6;
  const int lane = threadIdx.x & 63;
  const int wr = w >> 2, wc = w & 3;  // phase A: 2M x 4N waves
  const int rowBase = blockIdx.x << 7;
  const int sr = lane >> 2;
  const int sc = (lane & 3) << 3;
  const int ln = lane & 15;
  const int lh = lane >> 4;
  const int kg = lh << 3;

  f32x4 acc[4][4];
#pragma unroll
  for (int i = 0; i < 4; ++i)
#pragma unroll
    for (int j = 0; j < 4; ++j) acc[i][j] = (f32x4){0.f, 0.f, 0.f, 0.f};

#define STAGEH(bi, k0)                                                          \
  {                                                                             \
    const __bf16* ga = h1 + (size_t)(rowBase + (w << 4) + sr) * lda + (k0) + sc;\
    gl_lds16(ga, As + (bi)*4096 + (w << 4) * 32);                               \
    const __bf16* gb = WS + (size_t)((w << 5) + sr) * 512 + (k0) + sc;          \
    gl_lds16(gb, Bs + (bi)*8192 + (w << 5) * 32);                               \
    gl_lds16(gb + (size_t)16 * 512, Bs + (bi)*8192 + ((w << 5) + 16) * 32);     \
  }

  STAGEH(0, 0);
  __syncthreads();
  int buf = 0;
  for (int t = 0; t < 16; ++t) {  // K = 512
    if (t + 1 < 16) STAGEH(buf ^ 1, (t + 1) << 5);
    bf16x8 av[4], bv[4];
#pragma unroll
    for (int i = 0; i < 4; ++i)
      av[i] = *(const bf16x8*)&As[buf * 4096 + ((wr << 6) + (i << 4) + ln) * 32 + kg];
#pragma unroll
    for (int i = 0; i < 4; ++i)
      bv[i] = *(const bf16x8*)&Bs[buf * 8192 + ((wc << 6) + (i << 4) + ln) * 32 + kg];
#pragma unroll
    for (int mi = 0; mi < 4; ++mi)
#pragma unroll
      for (int ni = 0; ni < 4; ++ni)
        acc[mi][ni] = __builtin_amdgcn_mfma_f32_16x16x32_bf16(
            av[mi], bv[ni], acc[mi][ni], 0, 0, 0);
    __syncthreads();
    buf ^= 1;
  }
#undef STAGEH

  {
    const int rl0 = (wr << 6) + (lh << 2);
    const int cl0 = (wc << 6) + ln;
#pragma unroll
    for (int mi = 0; mi < 4; ++mi)
#pragma unroll
      for (int ni = 0; ni < 4; ++ni) {
        const int col = cl0 + (ni << 4);
        const float b = sh_b[col];
#pragma unroll
        for (int r = 0; r < 4; ++r) {
          float v = fmaxf(acc[mi][ni][r] + b, 0.f);
          hid[(rl0 + (mi << 4) + r) * 264 + col] = (__bf16)v;
        }
      }
  }
  __syncthreads();

  if (w < 4) {
    const int wr2 = w >> 1, wc2 = w & 1;
    f32x4 a2[4][4];
#pragma unroll
    for (int i = 0; i < 4; ++i)
#pragma unroll
      for (int j = 0; j < 4; ++j) a2[i][j] = (f32x4){0.f, 0.f, 0.f, 0.f};
    for (int t = 0; t < 8; ++t) {  // K = 256
      bf16x8 av[4], bv[4];
#pragma unroll
      for (int i = 0; i < 4; ++i)
        av[i] = *(const bf16x8*)&hid[((wr2 << 6) + (i << 4) + ln) * 264 + (t << 5) + kg];
#pragma unroll
      for (int i = 0; i < 4; ++i)
        bv[i] = *(const bf16x8*)&WP[(size_t)((wc2 << 6) + (i << 4) + ln) * 256 + (t << 5) + kg];
#pragma unroll
      for (int mi = 0; mi < 4; ++mi)
#pragma unroll
        for (int ni = 0; ni < 4; ++ni)
          a2[mi][ni] = __builtin_amdgcn_mfma_f32_16x16x32_bf16(
              av[mi], bv[ni], a2[mi][ni], 0, 0, 0);
    }
    const int row0 = rowBase + (wr2 << 6) + (lh << 2);
    const int col0 = (wc2 << 6) + ln;
#pragma unroll
    for (int mi = 0; mi < 4; ++mi)
#pragma unroll
      for (int ni = 0; ni < 4; ++ni) {
        const int col = col0 + (ni << 4);
        if (col < 100) {
          const float b = pred_b[col];
#pragma unroll
          for (int r = 0; r < 4; ++r)
            out[(size_t)(row0 + (mi << 4) + r) * 100 + col] =
                a2[mi][ni][r] + b;
        }
      }
  }
}

// ---------------------------------------------------------------------------
// pack_all: all 9 per-slot weight-pack regions in ONE launch (r10).
// ---------------------------------------------------------------------------
#define PR0 2621440
#define PR1 3670016
#define PR2 4325376
#define PR3 4980736
#define PR4 5242880
#define PR5 6291456
#define PR6 7340032
#define PR7 7471104
#define PR8 7503872
__global__ void pack_all(const float* __restrict__ W_ih0, const float* __restrict__ W_hh0,
                         const float* __restrict__ hwN_W0, const float* __restrict__ hwL_W0,
                         const float* __restrict__ W_ih1, const float* __restrict__ W_hh1,
                         const float* __restrict__ sh_W, const float* __restrict__ pred_W,
                         __bf16* __restrict__ WA, __bf16* __restrict__ WX,
                         __bf16* __restrict__ WH, __bf16* __restrict__ WB,
                         __bf16* __restrict__ WS, __bf16* __restrict__ WP, int s) {
  const int idx = blockIdx.x * 256 + threadIdx.x;
  if (idx >= PR8) return;
  if (idx < PR0) {
    int i = idx, r = i / 1280, c = i - r * 1280;
    int sr = (((r >> 4) & 3) << 9) + ((r >> 6) << 4) + (r & 15);
    WA[(long)r * 1792 + c] = (__bf16)W_ih0[(size_t)s * 2048 * 1280 + (long)sr * 1280 + c];
  } else if (idx < PR1) {
    int i = idx - PR0, r = i >> 9, c = i & 511;
    int sr = (((r >> 4) & 3) << 9) + ((r >> 6) << 4) + (r & 15);
    WA[(long)r * 1792 + 1280 + c] = (__bf16)W_hh0[(size_t)s * 2048 * 512 + (long)sr * 512 + c];
  } else if (idx < PR2) {
    int i = idx - PR1, r = i / 1280, c = i - r * 1280;
    WX[(long)r * 1280 + c] = (__bf16)hwN_W0[(size_t)s * 512 * 1792 + (long)r * 1792 + c];
  } else if (idx < PR3) {
    int i = idx - PR2, r = i / 1280, c = i - r * 1280;
    WX[(long)(512 + r) * 1280 + c] = (__bf16)hwL_W0[(size_t)s * 512 * 1280 + (long)r * 1280 + c];
  } else if (idx < PR4) {
    int i = idx - PR3, r = i >> 9, c = i & 511;
    WH[(long)r * 512 + c] = (__bf16)hwN_W0[(size_t)s * 512 * 1792 + (long)r * 1792 + 1280 + c];
  } else if (idx < PR5) {
    int i = idx - PR4, r = i >> 9, c = i & 511;
    int sr = (((r >> 4) & 3) << 9) + ((r >> 6) << 4) + (r & 15);
    WB[(long)r * 1024 + c] = (__bf16)W_ih1[(size_t)s * 2048 * 512 + (long)sr * 512 + c];
  } else if (idx < PR6) {
    int i = idx - PR5, r = i >> 9, c = i & 511;
    int sr = (((r >> 4) & 3) << 9) + ((r >> 6) << 4) + (r & 15);
    WB[(long)r * 1024 + 512 + c] = (__bf16)W_hh1[(size_t)s * 2048 * 512 + (long)sr * 512 + c];
  } else if (idx < PR7) {
    int i = idx - PR6, r = i >> 9, c = i & 511;
    WS[(long)r * 512 + c] = (__bf16)sh_W[(size_t)s * 256 * 512 + (long)r * 512 + c];
  } else {
    int i = idx - PR7, r = i >> 8, c = i & 255;
    float v = (r < 100) ? pred_W[(size_t)s * 100 * 256 + (long)r * 256 + c] : 0.f;
    WP[(long)r * 256 + c] = (__bf16)v;
  }
}

__global__ void conv_inputs(const float* __restrict__ in, __bf16* __restrict__ xh) {
  int idx = blockIdx.x * 256 + threadIdx.x;  // B*1024
  int b = idx >> 10, c = idx & 1023;
  xh[(size_t)b * 1792 + c] = (__bf16)in[idx];
}

__global__ void set_start(const float* __restrict__ start, __bf16* __restrict__ xh) {
  int idx = blockIdx.x * 256 + threadIdx.x;  // B*256
  int b = idx >> 8, e = idx & 255;
  xh[(size_t)b * 1792 + 1024 + e] = (__bf16)start[e];
}

__global__ void zero_states(__bf16* __restrict__ xh, __bf16* __restrict__ xh1A) {
  int idx = blockIdx.x * 256 + threadIdx.x;  // B*512
  int b = idx >> 9, h = idx & 511;
  xh[(size_t)b * 1792 + 1280 + h] = (__bf16)0.f;   // h0 = 0
  xh1A[(size_t)b * 1024 + 512 + h] = (__bf16)0.f;  // h1 = 0 (buffer 0)
}

extern "C" void kernel_launch(void* const* d_in, const int* in_sizes, int n_in,
                              void* d_out, int out_size, void* d_ws, size_t ws_size,
                              hipStream_t stream) {
  const float* inputs = (const float*)d_in[0];
  const int* labels = (const int*)d_in[1];
  const float* start = (const float*)d_in[2];
  const float* emb = (const float*)d_in[3];
  const float* W_ih0 = (const float*)d_in[4];
  const float* W_hh0 = (const float*)d_in[5];
  const float* b_ih0 = (const float*)d_in[6];
  const float* b_hh0 = (const float*)d_in[7];
  const float* hwN_W0 = (const float*)d_in[8];
  const float* hwN_b0 = (const float*)d_in[9];
  const float* hwL_W0 = (const float*)d_in[10];
  const float* W_ih1 = (const float*)d_in[11];
  const float* W_hh1 = (const float*)d_in[12];
  const float* b_ih1 = (const float*)d_in[13];
  const float* b_hh1 = (const float*)d_in[14];
  // d_in[15..17]: hwN_W1 / hwN_b1 / hwL_W1 — dead in reference, skipped
  const float* sh_W = (const float*)d_in[18];
  const float* sh_b = (const float*)d_in[19];
  const float* pred_W = (const float*)d_in[20];
  const float* pred_b = (const float*)d_in[21];
  float* out = (float*)d_out;

  char* p = (char*)d_ws;
  size_t off = 0;
  auto alloc = [&](size_t bytes) {
    void* r = p + off;
    off += (bytes + 255) & ~(size_t)255;
    return r;
  };
  __bf16* WA = (__bf16*)alloc((size_t)2048 * 1792 * 2);
  __bf16* WX = (__bf16*)alloc((size_t)1024 * 1280 * 2);
  __bf16* WH = (__bf16*)alloc((size_t)512 * 512 * 2);
  __bf16* WB = (__bf16*)alloc((size_t)2048 * 1024 * 2);
  __bf16* WS = (__bf16*)alloc((size_t)256 * 512 * 2);
  __bf16* WP = (__bf16*)alloc((size_t)128 * 256 * 2);
  __bf16* xh = (__bf16*)alloc((size_t)BATCH * 1792 * 2);
  __bf16* xh1A = (__bf16*)alloc((size_t)BATCH * 1024 * 2);
  __bf16* xh1B = (__bf16*)alloc((size_t)BATCH * 1024 * 2);
  __bf16* h0new = (__bf16*)alloc((size_t)BATCH * 512 * 2);
  __bf16* ghw = (__bf16*)alloc((size_t)BATCH * 1024 * 2);
  float* c0 = (float*)alloc((size_t)BATCH * 512 * 4);
  float* c1 = (float*)alloc((size_t)BATCH * 512 * 4);
  (void)ws_size; (void)in_sizes; (void)n_in; (void)out_size;

  hipMemsetAsync(c0, 0, (size_t)BATCH * 512 * 4, stream);
  hipMemsetAsync(c1, 0, (size_t)BATCH * 512 * 4, stream);
  zero_states<<<BATCH * 512 / 256, 256, 0, stream>>>(xh, xh1A);
  conv_inputs<<<BATCH * 1024 / 256, 256, 0, stream>>>(inputs, xh);
  set_start<<<BATCH * 256 / 256, 256, 0, stream>>>(start, xh);

  const dim3 blk(256);
  for (int s = 0; s < SLOTS; ++s) {
    __bf16* xcur = (s & 1) ? xh1B : xh1A;
    __bf16* xnext = (s & 1) ? xh1A : xh1B;
    // pack this slot's weights: single launch, 9 regions
    pack_all<<<(PR8 + 255) / 256, blk, 0, stream>>>(
        W_ih0, W_hh0, hwN_W0, hwL_W0, W_ih1, W_hh1, sh_W, pred_W,
        WA, WX, WH, WB, WS, WP, s);

    // aux GEMM: ghw = x[:,0:1280] @ WX^T (bf16)
    gemm_aux<<<dim3(8, 64), blk, 0, stream>>>(
        xh, 1792, WX, 1280, ghw, 1024, 1280);
    // GEMM0 (128², 4 blk/CU, XCD-swizzled, fused LSTM-0): h -> h0new, c0
    gemm_lstm<<<dim3(16, 64), blk, 0, stream>>>(
        xh, 1792, WA, 1792, b_ih0 + s * 2048, b_hh0 + s * 2048,
        c0, h0new, 512, 0, 1792);
    // hwy: acc = h0new @ WH^T; highway -> cur; h0new -> xh; fused emb write
    gemm_hwy<<<dim3(4, 64), blk, 0, stream>>>(
        h0new, 512, WH, 512, xcur, 1024, hwN_b0 + s * 512,
        ghw, xh, 1792, 1280, h0new,
        emb + (size_t)s * 100 * 256, labels + (size_t)s * BATCH,
        (s < SLOTS - 1) ? 1 : 0);
    // GEMM1: [cur|h1] @ WB^T -> fused LSTM-1 (h -> xnext[:,512:1024], c1)
    gemm_lstm<<<dim3(16, 64), blk, 0, stream>>>(
        xcur, 1024, WB, 1024, b_ih1 + s * 2048, b_hh1 + s * 2048,
        c1, xnext, 1024, 512, 1024);
    // head: hidden = relu(h1@WS^T+b) in LDS; logits = hidden@WP^T+b -> out[s]
    head_fused<<<64, 512, 116736, stream>>>(
        xnext + 512, 1024, WS, sh_b + s * 256, WP, pred_b + s * 100,
        out + (size_t)s * BATCH * 100);
  }
}

// Round 15
// 1508.550 us; speedup vs baseline: 1.0589x; 1.0268x over previous
//
#include <hip/hip_runtime.h>

#define SLOTS 7
#define BATCH 8192

typedef __attribute__((ext_vector_type(8))) __bf16 bf16x8;
typedef __attribute__((ext_vector_type(4))) float f32x4;

__device__ __forceinline__ void gl_lds16(const __bf16* g, __bf16* l) {
  __builtin_amdgcn_global_load_lds(
      (const __attribute__((address_space(1))) void*)g,
      (__attribute__((address_space(3))) void*)l, 16, 0, 0);
}

__device__ __forceinline__ float sigmoidf_(float x) {
  return 1.f / (1.f + __expf(-x));
}
__device__ __forceinline__ float tanhf_(float x) {
  float xc = fminf(fmaxf(x, -15.f), 15.f);
  float e = __expf(2.f * xc);
  return (e - 1.f) / (e + 1.f);
}

// bijective XCD swizzle (m157/m204): requires NB % 8 == 0 (all our grids).
__device__ __forceinline__ void xcd_remap(int& bx, int& by) {
  const int NBx = gridDim.x;
  const int NB = NBx * gridDim.y;
  int id = by * NBx + bx;
  id = (id & 7) * (NB >> 3) + (id >> 3);
  bx = id % NBx;
  by = id / NBx;
}

// ---------------------------------------------------------------------------
// gemm_lstm: 128x128 2-phase GEMM + fused gate-interleaved LSTM epilogue,
// held under the register cliff (r10/r11): 56 VGPR + 64 AGPR <= 128 -> 4
// blk/CU via __launch_bounds__(256,4); bias loads AFTER the K-loop.
// r7-verified 0-conflict chunk swizzle (both-sides, rule #21).
// r13 lesson: keep per-XCD working set ~WA+xh (no extra fused panels).
// Slot-0 exact-math: state==0 -> caller passes truncated K (1280 / 512).
// Epilogue: col c -> gate (c>>4)&3 of unit h=(c>>6)*16+(c&15).
// ---------------------------------------------------------------------------
__global__ void __launch_bounds__(256, 4)
gemm_lstm(const __bf16* __restrict__ A, int lda,
          const __bf16* __restrict__ Bw, int ldb,
          const float* __restrict__ b_ih, const float* __restrict__ b_hh,
          float* __restrict__ cst, __bf16* __restrict__ hout, int hld, int hoff,
          int K) {
  __shared__ __align__(16) __bf16 As[2][128 * 32];
  __shared__ __align__(16) __bf16 Bs[2][128 * 32];
  const int w = threadIdx.x >> 6;
  const int lane = threadIdx.x & 63;
  const int wr = w >> 1, wc = w & 1;
  int bx = blockIdx.x, by = blockIdx.y;
  xcd_remap(bx, by);
  const int rowBase = by << 7;
  const int colBase = bx << 7;
  const int sr = lane >> 2;
  const int scs = (((lane & 3) ^ ((sr >> 1) & 3)) << 3);  // swizzled src chunk

  f32x4 acc[4][4];
#pragma unroll
  for (int i = 0; i < 4; ++i)
#pragma unroll
    for (int j = 0; j < 4; ++j) acc[i][j] = (f32x4){0.f, 0.f, 0.f, 0.f};

  const int nsteps = K >> 5;

#define STAGE(bi, k0)                                                            \
  {                                                                              \
    const __bf16* ga = A + (size_t)(rowBase + (w << 5) + sr) * lda + (k0) + scs; \
    gl_lds16(ga, &As[(bi)][(w << 5) * 32]);                                      \
    gl_lds16(ga + (size_t)16 * lda, &As[(bi)][((w << 5) + 16) * 32]);            \
    const __bf16* gb = Bw + (size_t)(colBase + (w << 5) + sr) * ldb + (k0) + scs;\
    gl_lds16(gb, &Bs[(bi)][(w << 5) * 32]);                                      \
    gl_lds16(gb + (size_t)16 * ldb, &Bs[(bi)][((w << 5) + 16) * 32]);            \
  }

  STAGE(0, 0);
  __syncthreads();
  int buf = 0;
  const int ln = lane & 15;
  const int lh = lane >> 4;
  const int swz = ((lh ^ ((ln >> 1) & 3)) << 3);  // swizzled read offset
  for (int t = 0; t < nsteps; ++t) {
    if (t + 1 < nsteps) STAGE(buf ^ 1, (t + 1) << 5);
    bf16x8 av[4], bv[4];
#pragma unroll
    for (int i = 0; i < 4; ++i)
      av[i] = *(const bf16x8*)&As[buf][((wr << 6) + (i << 4) + ln) * 32 + swz];
#pragma unroll
    for (int i = 0; i < 4; ++i)
      bv[i] = *(const bf16x8*)&Bs[buf][((wc << 6) + (i << 4) + ln) * 32 + swz];
#pragma unroll
    for (int mi = 0; mi < 4; ++mi)
#pragma unroll
      for (int ni = 0; ni < 4; ++ni)
        acc[mi][ni] = __builtin_amdgcn_mfma_f32_16x16x32_bf16(
            av[mi], bv[ni], acc[mi][ni], 0, 0, 0);
    __syncthreads();
    buf ^= 1;
  }
#undef STAGE

  const int row0 = rowBase + (wr << 6) + (lh << 2);
  const int h = (((colBase >> 6) + wc) << 4) + ln;
  const float bs0 = b_ih[h] + b_hh[h];
  const float bs1 = b_ih[512 + h] + b_hh[512 + h];
  const float bs2 = b_ih[1024 + h] + b_hh[1024 + h];
  const float bs3 = b_ih[1536 + h] + b_hh[1536 + h];
#pragma unroll
  for (int mi = 0; mi < 4; ++mi)
#pragma unroll
    for (int r = 0; r < 4; ++r) {
      const int row = row0 + (mi << 4) + r;
      float gi = sigmoidf_(acc[mi][0][r] + bs0);
      float gf = sigmoidf_(acc[mi][1][r] + bs1);
      float gg = tanhf_(acc[mi][2][r] + bs2);
      float go = sigmoidf_(acc[mi][3][r] + bs3);
      const size_t ci = (size_t)row * 512 + h;
      float cn = gf * cst[ci] + gi * gg;
      cst[ci] = cn;
      hout[(size_t)row * hld + hoff + h] = (__bf16)(go * tanhf_(cn));
    }
}

// ---------------------------------------------------------------------------
// gemm_aux: 2-phase 128x128 GEMM, bf16 plain store (ghw = x[:,0:1280]@WX^T).
// ---------------------------------------------------------------------------
__global__ void __launch_bounds__(256)
gemm_aux(const __bf16* __restrict__ A, int lda,
         const __bf16* __restrict__ Bw, int ldb,
         __bf16* __restrict__ Cout, int ldc, int K) {
  __shared__ __align__(16) __bf16 As[2][128 * 32];
  __shared__ __align__(16) __bf16 Bs[2][128 * 32];
  const int w = threadIdx.x >> 6;
  const int lane = threadIdx.x & 63;
  const int wr = w >> 1, wc = w & 1;
  int bx = blockIdx.x, by = blockIdx.y;
  xcd_remap(bx, by);
  const int rowBase = by << 7;
  const int colBase = bx << 7;
  const int sr = lane >> 2;
  const int sc = (lane & 3) << 3;

  f32x4 acc[4][4];
#pragma unroll
  for (int i = 0; i < 4; ++i)
#pragma unroll
    for (int j = 0; j < 4; ++j) acc[i][j] = (f32x4){0.f, 0.f, 0.f, 0.f};

  const int nsteps = K >> 5;

#define STAGE(bi, k0)                                                           \
  {                                                                             \
    const __bf16* ga = A + (size_t)(rowBase + (w << 5) + sr) * lda + (k0) + sc; \
    gl_lds16(ga, &As[(bi)][(w << 5) * 32]);                                     \
    gl_lds16(ga + (size_t)16 * lda, &As[(bi)][((w << 5) + 16) * 32]);           \
    const __bf16* gb = Bw + (size_t)(colBase + (w << 5) + sr) * ldb + (k0) + sc;\
    gl_lds16(gb, &Bs[(bi)][(w << 5) * 32]);                                     \
    gl_lds16(gb + (size_t)16 * ldb, &Bs[(bi)][((w << 5) + 16) * 32]);           \
  }

  STAGE(0, 0);
  __syncthreads();
  int buf = 0;
  const int ln = lane & 15;
  const int kg = (lane >> 4) << 3;
  for (int t = 0; t < nsteps; ++t) {
    if (t + 1 < nsteps) STAGE(buf ^ 1, (t + 1) << 5);
    bf16x8 av[4], bv[4];
#pragma unroll
    for (int i = 0; i < 4; ++i)
      av[i] = *(const bf16x8*)&As[buf][((wr << 6) + (i << 4) + ln) * 32 + kg];
#pragma unroll
    for (int i = 0; i < 4; ++i)
      bv[i] = *(const bf16x8*)&Bs[buf][((wc << 6) + (i << 4) + ln) * 32 + kg];
#pragma unroll
    for (int mi = 0; mi < 4; ++mi)
#pragma unroll
      for (int ni = 0; ni < 4; ++ni)
        acc[mi][ni] = __builtin_amdgcn_mfma_f32_16x16x32_bf16(
            av[mi], bv[ni], acc[mi][ni], 0, 0, 0);
    __syncthreads();
    buf ^= 1;
  }
#undef STAGE

  const int lh = lane >> 4;
  const int row0 = rowBase + (wr << 6) + (lh << 2);
  const int col0 = colBase + (wc << 6) + ln;
#pragma unroll
  for (int mi = 0; mi < 4; ++mi)
#pragma unroll
    for (int ni = 0; ni < 4; ++ni) {
      const int col = col0 + (ni << 4);
#pragma unroll
      for (int r = 0; r < 4; ++r)
        Cout[(size_t)(row0 + (mi << 4) + r) * ldc + col] = (__bf16)acc[mi][ni][r];
    }
}

// ---------------------------------------------------------------------------
// gemm_hwy: 2-phase 128x128 GEMM (K=512), highway epilogue + fused
// teacher-forced embedding write (r12-validated).
// ---------------------------------------------------------------------------
__global__ void __launch_bounds__(256)
gemm_hwy(const __bf16* __restrict__ A, int lda,
         const __bf16* __restrict__ Bw, int ldb,
         __bf16* __restrict__ Cout, int ldc,
         const float* __restrict__ bias,
         const __bf16* __restrict__ auxr,
         __bf16* __restrict__ hout, int hld, int hoff,
         const __bf16* __restrict__ hsrc,
         const float* __restrict__ embp, const int* __restrict__ labels,
         int do_emb) {
  __shared__ __align__(16) __bf16 As[2][128 * 32];
  __shared__ __align__(16) __bf16 Bs[2][128 * 32];
  const int w = threadIdx.x >> 6;
  const int lane = threadIdx.x & 63;
  const int wr = w >> 1, wc = w & 1;
  int bx = blockIdx.x, by = blockIdx.y;
  xcd_remap(bx, by);
  const int rowBase = by << 7;
  const int colBase = bx << 7;
  const int sr = lane >> 2;
  const int sc = (lane & 3) << 3;

  f32x4 acc[4][4];
#pragma unroll
  for (int i = 0; i < 4; ++i)
#pragma unroll
    for (int j = 0; j < 4; ++j) acc[i][j] = (f32x4){0.f, 0.f, 0.f, 0.f};

#define STAGE(bi, k0)                                                           \
  {                                                                             \
    const __bf16* ga = A + (size_t)(rowBase + (w << 5) + sr) * lda + (k0) + sc; \
    gl_lds16(ga, &As[(bi)][(w << 5) * 32]);                                     \
    gl_lds16(ga + (size_t)16 * lda, &As[(bi)][((w << 5) + 16) * 32]);           \
    const __bf16* gb = Bw + (size_t)(colBase + (w << 5) + sr) * ldb + (k0) + sc;\
    gl_lds16(gb, &Bs[(bi)][(w << 5) * 32]);                                     \
    gl_lds16(gb + (size_t)16 * ldb, &Bs[(bi)][((w << 5) + 16) * 32]);           \
  }

  STAGE(0, 0);
  __syncthreads();
  int buf = 0;
  const int ln = lane & 15;
  const int kg = (lane >> 4) << 3;
  for (int t = 0; t < 16; ++t) {  // K = 512
    if (t + 1 < 16) STAGE(buf ^ 1, (t + 1) << 5);
    bf16x8 av[4], bv[4];
#pragma unroll
    for (int i = 0; i < 4; ++i)
      av[i] = *(const bf16x8*)&As[buf][((wr << 6) + (i << 4) + ln) * 32 + kg];
#pragma unroll
    for (int i = 0; i < 4; ++i)
      bv[i] = *(const bf16x8*)&Bs[buf][((wc << 6) + (i << 4) + ln) * 32 + kg];
#pragma unroll
    for (int mi = 0; mi < 4; ++mi)
#pragma unroll
      for (int ni = 0; ni < 4; ++ni)
        acc[mi][ni] = __builtin_amdgcn_mfma_f32_16x16x32_bf16(
            av[mi], bv[ni], acc[mi][ni], 0, 0, 0);
    __syncthreads();
    buf ^= 1;
  }
#undef STAGE

  const int lh = lane >> 4;
  const int row0 = rowBase + (wr << 6) + (lh << 2);
  const int col0 = colBase + (wc << 6) + ln;
#pragma unroll
  for (int mi = 0; mi < 4; ++mi)
#pragma unroll
    for (int ni = 0; ni < 4; ++ni) {
      const int col = col0 + (ni << 4);
#pragma unroll
      for (int r = 0; r < 4; ++r) {
        const int row = row0 + (mi << 4) + r;
        float xp = (float)auxr[(size_t)row * 1024 + col];
        float hwl = (float)auxr[(size_t)row * 1024 + 512 + col];
        float gn = sigmoidf_(acc[mi][ni][r] + xp + bias[col]);
        float hn = (float)hsrc[(size_t)row * 512 + col];
        Cout[(size_t)row * ldc + col] = (__bf16)(gn * hn + (1.f - gn) * hwl);
        hout[(size_t)row * hld + hoff + col] = (__bf16)hn;  // h0 -> xh
      }
    }
  // teacher-forced embedding: cols 0..255 covered once by colBase<256 blocks
  if (do_emb && colBase < 256) {
#pragma unroll
    for (int mi = 0; mi < 4; ++mi)
#pragma unroll
      for (int r = 0; r < 4; ++r) {
        const int row = row0 + (mi << 4) + r;
        const int lab = labels[row];
#pragma unroll
        for (int ni = 0; ni < 4; ++ni) {
          const int col = col0 + (ni << 4);
          hout[(size_t)row * hld + 1024 + col] =
              (__bf16)embp[(size_t)lab * 256 + col];
        }
      }
  }
}

// ---------------------------------------------------------------------------
// head_fused (r13-validated win): sh + pred in one kernel. 64 blocks x 512.
// Phase A (8 waves): hidden[128x256] = relu(h1@WS^T + sh_b) -> LDS [128][264].
// Phase B (4 waves): out[128x100] = hidden @ WP^T + pred_b; WP from global.
// ---------------------------------------------------------------------------
__global__ void __launch_bounds__(512)
head_fused(const __bf16* __restrict__ h1, int lda,
           const __bf16* __restrict__ WS, const float* __restrict__ sh_b,
           const __bf16* __restrict__ WP, const float* __restrict__ pred_b,
           float* __restrict__ out) {
  extern __shared__ __bf16 dls[];
  __bf16* As = dls;           // 2 x 128x32 = 8192
  __bf16* Bs = dls + 8192;    // 2 x 256x32 = 16384
  __bf16* hid = dls + 24576;  // 128 x 264 = 33792
  const int w = threadIdx.x >> 6;
  const int lane = threadIdx.x & 63;
  const int wr = w >> 2, wc = w & 3;  // phase A: 2M x 4N waves
  const int rowBase = blockIdx.x << 7;
  const int sr = lane >> 2;
  const int sc = (lane & 3) << 3;
  const int ln = lane & 15;
  const int lh = lane >> 4;
  const int kg = lh << 3;

  f32x4 acc[4][4];
#pragma unroll
  for (int i = 0; i < 4; ++i)
#pragma unroll
    for (int j = 0; j < 4; ++j) acc[i][j] = (f32x4){0.f, 0.f, 0.f, 0.f};

#define STAGEH(bi, k0)                                                          \
  {                                                                             \
    const __bf16* ga = h1 + (size_t)(rowBase + (w << 4) + sr) * lda + (k0) + sc;\
    gl_lds16(ga, As + (bi)*4096 + (w << 4) * 32);                               \
    const __bf16* gb = WS + (size_t)((w << 5) + sr) * 512 + (k0) + sc;          \
    gl_lds16(gb, Bs + (bi)*8192 + (w << 5) * 32);                               \
    gl_lds16(gb + (size_t)16 * 512, Bs + (bi)*8192 + ((w << 5) + 16) * 32);     \
  }

  STAGEH(0, 0);
  __syncthreads();
  int buf = 0;
  for (int t = 0; t < 16; ++t) {  // K = 512
    if (t + 1 < 16) STAGEH(buf ^ 1, (t + 1) << 5);
    bf16x8 av[4], bv[4];
#pragma unroll
    for (int i = 0; i < 4; ++i)
      av[i] = *(const bf16x8*)&As[buf * 4096 + ((wr << 6) + (i << 4) + ln) * 32 + kg];
#pragma unroll
    for (int i = 0; i < 4; ++i)
      bv[i] = *(const bf16x8*)&Bs[buf * 8192 + ((wc << 6) + (i << 4) + ln) * 32 + kg];
#pragma unroll
    for (int mi = 0; mi < 4; ++mi)
#pragma unroll
      for (int ni = 0; ni < 4; ++ni)
        acc[mi][ni] = __builtin_amdgcn_mfma_f32_16x16x32_bf16(
            av[mi], bv[ni], acc[mi][ni], 0, 0, 0);
    __syncthreads();
    buf ^= 1;
  }
#undef STAGEH

  {
    const int rl0 = (wr << 6) + (lh << 2);
    const int cl0 = (wc << 6) + ln;
#pragma unroll
    for (int mi = 0; mi < 4; ++mi)
#pragma unroll
      for (int ni = 0; ni < 4; ++ni) {
        const int col = cl0 + (ni << 4);
        const float b = sh_b[col];
#pragma unroll
        for (int r = 0; r < 4; ++r) {
          float v = fmaxf(acc[mi][ni][r] + b, 0.f);
          hid[(rl0 + (mi << 4) + r) * 264 + col] = (__bf16)v;
        }
      }
  }
  __syncthreads();

  if (w < 4) {
    const int wr2 = w >> 1, wc2 = w & 1;
    f32x4 a2[4][4];
#pragma unroll
    for (int i = 0; i < 4; ++i)
#pragma unroll
      for (int j = 0; j < 4; ++j) a2[i][j] = (f32x4){0.f, 0.f, 0.f, 0.f};
    for (int t = 0; t < 8; ++t) {  // K = 256
      bf16x8 av[4], bv[4];
#pragma unroll
      for (int i = 0; i < 4; ++i)
        av[i] = *(const bf16x8*)&hid[((wr2 << 6) + (i << 4) + ln) * 264 + (t << 5) + kg];
#pragma unroll
      for (int i = 0; i < 4; ++i)
        bv[i] = *(const bf16x8*)&WP[(size_t)((wc2 << 6) + (i << 4) + ln) * 256 + (t << 5) + kg];
#pragma unroll
      for (int mi = 0; mi < 4; ++mi)
#pragma unroll
        for (int ni = 0; ni < 4; ++ni)
          a2[mi][ni] = __builtin_amdgcn_mfma_f32_16x16x32_bf16(
              av[mi], bv[ni], a2[mi][ni], 0, 0, 0);
    }
    const int row0 = rowBase + (wr2 << 6) + (lh << 2);
    const int col0 = (wc2 << 6) + ln;
#pragma unroll
    for (int mi = 0; mi < 4; ++mi)
#pragma unroll
      for (int ni = 0; ni < 4; ++ni) {
        const int col = col0 + (ni << 4);
        if (col < 100) {
          const float b = pred_b[col];
#pragma unroll
          for (int r = 0; r < 4; ++r)
            out[(size_t)(row0 + (mi << 4) + r) * 100 + col] =
                a2[mi][ni][r] + b;
        }
      }
  }
}

// ---------------------------------------------------------------------------
// pack_all: all 9 per-slot weight-pack regions in ONE launch (r10).
// ---------------------------------------------------------------------------
#define PR0 2621440
#define PR1 3670016
#define PR2 4325376
#define PR3 4980736
#define PR4 5242880
#define PR5 6291456
#define PR6 7340032
#define PR7 7471104
#define PR8 7503872
__global__ void pack_all(const float* __restrict__ W_ih0, const float* __restrict__ W_hh0,
                         const float* __restrict__ hwN_W0, const float* __restrict__ hwL_W0,
                         const float* __restrict__ W_ih1, const float* __restrict__ W_hh1,
                         const float* __restrict__ sh_W, const float* __restrict__ pred_W,
                         __bf16* __restrict__ WA, __bf16* __restrict__ WX,
                         __bf16* __restrict__ WH, __bf16* __restrict__ WB,
                         __bf16* __restrict__ WS, __bf16* __restrict__ WP, int s) {
  const int idx = blockIdx.x * 256 + threadIdx.x;
  if (idx >= PR8) return;
  if (idx < PR0) {
    int i = idx, r = i / 1280, c = i - r * 1280;
    int sr = (((r >> 4) & 3) << 9) + ((r >> 6) << 4) + (r & 15);
    WA[(long)r * 1792 + c] = (__bf16)W_ih0[(size_t)s * 2048 * 1280 + (long)sr * 1280 + c];
  } else if (idx < PR1) {
    int i = idx - PR0, r = i >> 9, c = i & 511;
    int sr = (((r >> 4) & 3) << 9) + ((r >> 6) << 4) + (r & 15);
    WA[(long)r * 1792 + 1280 + c] = (__bf16)W_hh0[(size_t)s * 2048 * 512 + (long)sr * 512 + c];
  } else if (idx < PR2) {
    int i = idx - PR1, r = i / 1280, c = i - r * 1280;
    WX[(long)r * 1280 + c] = (__bf16)hwN_W0[(size_t)s * 512 * 1792 + (long)r * 1792 + c];
  } else if (idx < PR3) {
    int i = idx - PR2, r = i / 1280, c = i - r * 1280;
    WX[(long)(512 + r) * 1280 + c] = (__bf16)hwL_W0[(size_t)s * 512 * 1280 + (long)r * 1280 + c];
  } else if (idx < PR4) {
    int i = idx - PR3, r = i >> 9, c = i & 511;
    WH[(long)r * 512 + c] = (__bf16)hwN_W0[(size_t)s * 512 * 1792 + (long)r * 1792 + 1280 + c];
  } else if (idx < PR5) {
    int i = idx - PR4, r = i >> 9, c = i & 511;
    int sr = (((r >> 4) & 3) << 9) + ((r >> 6) << 4) + (r & 15);
    WB[(long)r * 1024 + c] = (__bf16)W_ih1[(size_t)s * 2048 * 512 + (long)sr * 512 + c];
  } else if (idx < PR6) {
    int i = idx - PR5, r = i >> 9, c = i & 511;
    int sr = (((r >> 4) & 3) << 9) + ((r >> 6) << 4) + (r & 15);
    WB[(long)r * 1024 + 512 + c] = (__bf16)W_hh1[(size_t)s * 2048 * 512 + (long)sr * 512 + c];
  } else if (idx < PR7) {
    int i = idx - PR6, r = i >> 9, c = i & 511;
    WS[(long)r * 512 + c] = (__bf16)sh_W[(size_t)s * 256 * 512 + (long)r * 512 + c];
  } else {
    int i = idx - PR7, r = i >> 8, c = i & 255;
    float v = (r < 100) ? pred_W[(size_t)s * 100 * 256 + (long)r * 256 + c] : 0.f;
    WP[(long)r * 256 + c] = (__bf16)v;
  }
}

__global__ void conv_inputs(const float* __restrict__ in, __bf16* __restrict__ xh) {
  int idx = blockIdx.x * 256 + threadIdx.x;  // B*1024
  int b = idx >> 10, c = idx & 1023;
  xh[(size_t)b * 1792 + c] = (__bf16)in[idx];
}

__global__ void set_start(const float* __restrict__ start, __bf16* __restrict__ xh) {
  int idx = blockIdx.x * 256 + threadIdx.x;  // B*256
  int b = idx >> 8, e = idx & 255;
  xh[(size_t)b * 1792 + 1024 + e] = (__bf16)start[e];
}

extern "C" void kernel_launch(void* const* d_in, const int* in_sizes, int n_in,
                              void* d_out, int out_size, void* d_ws, size_t ws_size,
                              hipStream_t stream) {
  const float* inputs = (const float*)d_in[0];
  const int* labels = (const int*)d_in[1];
  const float* start = (const float*)d_in[2];
  const float* emb = (const float*)d_in[3];
  const float* W_ih0 = (const float*)d_in[4];
  const float* W_hh0 = (const float*)d_in[5];
  const float* b_ih0 = (const float*)d_in[6];
  const float* b_hh0 = (const float*)d_in[7];
  const float* hwN_W0 = (const float*)d_in[8];
  const float* hwN_b0 = (const float*)d_in[9];
  const float* hwL_W0 = (const float*)d_in[10];
  const float* W_ih1 = (const float*)d_in[11];
  const float* W_hh1 = (const float*)d_in[12];
  const float* b_ih1 = (const float*)d_in[13];
  const float* b_hh1 = (const float*)d_in[14];
  // d_in[15..17]: hwN_W1 / hwN_b1 / hwL_W1 — dead in reference, skipped
  const float* sh_W = (const float*)d_in[18];
  const float* sh_b = (const float*)d_in[19];
  const float* pred_W = (const float*)d_in[20];
  const float* pred_b = (const float*)d_in[21];
  float* out = (float*)d_out;

  char* p = (char*)d_ws;
  size_t off = 0;
  auto alloc = [&](size_t bytes) {
    void* r = p + off;
    off += (bytes + 255) & ~(size_t)255;
    return r;
  };
  __bf16* WA = (__bf16*)alloc((size_t)2048 * 1792 * 2);
  __bf16* WX = (__bf16*)alloc((size_t)1024 * 1280 * 2);
  __bf16* WH = (__bf16*)alloc((size_t)512 * 512 * 2);
  __bf16* WB = (__bf16*)alloc((size_t)2048 * 1024 * 2);
  __bf16* WS = (__bf16*)alloc((size_t)256 * 512 * 2);
  __bf16* WP = (__bf16*)alloc((size_t)128 * 256 * 2);
  __bf16* xh = (__bf16*)alloc((size_t)BATCH * 1792 * 2);
  __bf16* xh1A = (__bf16*)alloc((size_t)BATCH * 1024 * 2);
  __bf16* xh1B = (__bf16*)alloc((size_t)BATCH * 1024 * 2);
  __bf16* h0new = (__bf16*)alloc((size_t)BATCH * 512 * 2);
  __bf16* ghw = (__bf16*)alloc((size_t)BATCH * 1024 * 2);
  float* c0 = (float*)alloc((size_t)BATCH * 512 * 4);
  float* c1 = (float*)alloc((size_t)BATCH * 512 * 4);
  (void)ws_size; (void)in_sizes; (void)n_in; (void)out_size;

  hipMemsetAsync(c0, 0, (size_t)BATCH * 512 * 4, stream);
  hipMemsetAsync(c1, 0, (size_t)BATCH * 512 * 4, stream);
  conv_inputs<<<BATCH * 1024 / 256, 256, 0, stream>>>(inputs, xh);
  set_start<<<BATCH * 256 / 256, 256, 0, stream>>>(start, xh);
  // NOTE: no zero_states — slot-0 GEMMs use truncated K (state==0 exactly),
  // so xh[:,1280:1792] and xh1A[:,512:1024] are write-before-read.

  const dim3 blk(256);
  for (int s = 0; s < SLOTS; ++s) {
    __bf16* xcur = (s & 1) ? xh1B : xh1A;
    __bf16* xnext = (s & 1) ? xh1A : xh1B;
    const int K0 = (s == 0) ? 1280 : 1792;  // slot 0: h0 == 0, skip W_hh0 slice
    const int K1 = (s == 0) ? 512 : 1024;   // slot 0: h1 == 0, skip W_hh1 slice
    // pack this slot's weights: single launch, 9 regions
    pack_all<<<(PR8 + 255) / 256, blk, 0, stream>>>(
        W_ih0, W_hh0, hwN_W0, hwL_W0, W_ih1, W_hh1, sh_W, pred_W,
        WA, WX, WH, WB, WS, WP, s);

    // aux GEMM: ghw = x[:,0:1280] @ WX^T (bf16)
    gemm_aux<<<dim3(8, 64), blk, 0, stream>>>(
        xh, 1792, WX, 1280, ghw, 1024, 1280);
    // GEMM0 (128², 4 blk/CU, XCD-swizzled, fused LSTM-0): h -> h0new, c0
    gemm_lstm<<<dim3(16, 64), blk, 0, stream>>>(
        xh, 1792, WA, 1792, b_ih0 + s * 2048, b_hh0 + s * 2048,
        c0, h0new, 512, 0, K0);
    // hwy: acc = h0new @ WH^T; highway -> cur; h0new -> xh; fused emb write
    gemm_hwy<<<dim3(4, 64), blk, 0, stream>>>(
        h0new, 512, WH, 512, xcur, 1024, hwN_b0 + s * 512,
        ghw, xh, 1792, 1280, h0new,
        emb + (size_t)s * 100 * 256, labels + (size_t)s * BATCH,
        (s < SLOTS - 1) ? 1 : 0);
    // GEMM1: [cur|h1] @ WB^T -> fused LSTM-1 (h -> xnext[:,512:1024], c1)
    gemm_lstm<<<dim3(16, 64), blk, 0, stream>>>(
        xcur, 1024, WB, 1024, b_ih1 + s * 2048, b_hh1 + s * 2048,
        c1, xnext, 1024, 512, K1);
    // head: hidden = relu(h1@WS^T+b) in LDS; logits = hidden@WP^T+b -> out[s]
    head_fused<<<64, 512, 116736, stream>>>(
        xnext + 512, 1024, WS, sh_b + s * 256, WP, pred_b + s * 100,
        out + (size_t)s * BATCH * 100);
  }
}